// Round 1
// baseline (322.776 us; speedup 1.0000x reference)
//
#include <hip/hip_runtime.h>
#include <math.h>

#define EMBED 768
#define NTOK  4096
#define NB    4
#define ROWS  (NB * NTOK)   // 16384
#define CN    192           // Q(64)|K(64)|V(64) concatenated output cols

// ---------------------------------------------------------------------------
// Kernel A: C[ROWS][192] = x @ [Wq|Wk|Wv] + [bq|bk|bv]
// BM=64 rows/block, BN=192 (all cols), BK=16. 256 threads, 4x12 micro-tile.
// x staged transposed into LDS (stride 68 -> worst 2-way bank alias = free),
// W tile staged [k][c]; all inner-loop LDS reads are float4 (ds_read_b128).
// ---------------------------------------------------------------------------
#define BM 64
#define BK 16

__global__ __launch_bounds__(256) void qkv_gemm(
    const float* __restrict__ x,
    const float* __restrict__ Wq, const float* __restrict__ bq,
    const float* __restrict__ Wk, const float* __restrict__ bk,
    const float* __restrict__ Wv, const float* __restrict__ bv,
    float* __restrict__ C) {
  __shared__ float xs[BK][68];   // [k][row], stride 68 words
  __shared__ float ws[BK][CN];   // [k][col]

  const int t  = threadIdx.x;
  const int tx = t & 15;         // col group: cols 12*tx .. 12*tx+11
  const int ty = t >> 4;         // row group: rows 4*ty .. 4*ty+3
  const int row0 = blockIdx.x * BM;

  float acc[4][12];
#pragma unroll
  for (int r = 0; r < 4; ++r)
#pragma unroll
    for (int j = 0; j < 12; ++j) acc[r][j] = 0.f;

  const int lk = t & 15;   // k index for staging x
  const int lr = t >> 4;   // base row for staging x

  for (int k0 = 0; k0 < EMBED; k0 += BK) {
    // stage x tile (64 rows x 16 k), transposed
#pragma unroll
    for (int rr = 0; rr < 4; ++rr) {
      int row = lr + rr * 16;
      xs[lk][row] = x[(size_t)(row0 + row) * EMBED + k0 + lk];
    }
    // stage W tile: 16 x 192 = 3072 elements, 12 per thread, coalesced in c
#pragma unroll
    for (int j = 0; j < 12; ++j) {
      int e  = t + j * 256;
      int kk = e / CN;
      int c  = e - kk * CN;
      float w;
      if (c < 64)        w = Wq[(size_t)(k0 + kk) * 64 + c];
      else if (c < 128)  w = Wk[(size_t)(k0 + kk) * 64 + (c - 64)];
      else               w = Wv[(size_t)(k0 + kk) * 64 + (c - 128)];
      ws[kk][c] = w;
    }
    __syncthreads();

#pragma unroll
    for (int kk = 0; kk < BK; ++kk) {
      float4 a  = *(const float4*)&xs[kk][ty * 4];
      float4 b0 = *(const float4*)&ws[kk][tx * 12];
      float4 b1 = *(const float4*)&ws[kk][tx * 12 + 4];
      float4 b2 = *(const float4*)&ws[kk][tx * 12 + 8];
      const float av[4]  = {a.x, a.y, a.z, a.w};
      const float bb[12] = {b0.x, b0.y, b0.z, b0.w,
                            b1.x, b1.y, b1.z, b1.w,
                            b2.x, b2.y, b2.z, b2.w};
#pragma unroll
      for (int r = 0; r < 4; ++r)
#pragma unroll
        for (int j = 0; j < 12; ++j)
          acc[r][j] += av[r] * bb[j];
    }
    __syncthreads();
  }

  // epilogue: bias + vectorized store
  float bias[12];
#pragma unroll
  for (int j = 0; j < 12; ++j) {
    int c = tx * 12 + j;
    bias[j] = (c < 64) ? bq[c] : (c < 128) ? bk[c - 64] : bv[c - 128];
  }
#pragma unroll
  for (int r = 0; r < 4; ++r) {
    int row = row0 + ty * 4 + r;
    float o[12];
#pragma unroll
    for (int j = 0; j < 12; ++j) o[j] = acc[r][j] + bias[j];
    float4* dst = (float4*)&C[(size_t)row * CN + tx * 12];
    dst[0] = make_float4(o[0], o[1], o[2],  o[3]);
    dst[1] = make_float4(o[4], o[5], o[6],  o[7]);
    dst[2] = make_float4(o[8], o[9], o[10], o[11]);
  }
}

// ---------------------------------------------------------------------------
// Kernel B: Vsum[b][d] = sum_r V[b,r,d].  256 blocks (64/batch, 64 rows each),
// LDS partial reduce, one atomicAdd per (block, d). Vsum pre-zeroed by memset.
// ---------------------------------------------------------------------------
__global__ __launch_bounds__(256) void vsum_kernel(const float* __restrict__ C,
                                                   float* __restrict__ Vsum) {
  __shared__ float red[4][64];
  const int t = threadIdx.x;
  const int d = t & 63;
  const int g = t >> 6;
  const int batch = blockIdx.x >> 6;
  const int chunk = blockIdx.x & 63;
  const size_t base =
      ((size_t)batch * NTOK + (size_t)chunk * 64 + (size_t)g * 16) * CN + 128 + d;
  float s = 0.f;
#pragma unroll
  for (int rr = 0; rr < 16; ++rr) s += C[base + (size_t)rr * CN];
  red[g][d] = s;
  __syncthreads();
  if (g == 0) {
    atomicAdd(&Vsum[batch * 64 + d],
              red[0][d] + red[1][d] + red[2][d] + red[3][d]);
  }
}

// ---------------------------------------------------------------------------
// Kernel C: per-row scores + softmax-with-zero-background + V combine.
// One wave per row (4 waves/block). Faithful to the reference quirk:
// softmax over [s0, s1, s2, 0 x (N-3)], output mixes V rows 0,1,2 + Vsum.
// ---------------------------------------------------------------------------
__global__ __launch_bounds__(256) void attn_kernel(const float* __restrict__ C,
                                                   const float* __restrict__ Vsum,
                                                   float* __restrict__ out) {
  const int t    = threadIdx.x;
  const int lane = t & 63;
  const int wave = t >> 6;
  const int r = blockIdx.x * 4 + wave;   // global row in [0, ROWS)
  const int b = r >> 12;                 // r / 4096
  const int i = r & (NTOK - 1);          // row within batch

  const float q   = C[(size_t)r * CN + lane];
  const float kc  = C[(size_t)r * CN + 64 + lane];
  float km = 0.f, kp = 0.f;
  if (i > 0)        km = C[(size_t)(r - 1) * CN + 64 + lane];
  if (i < NTOK - 1) kp = C[(size_t)(r + 1) * CN + 64 + lane];

  float p0 = q * km, p1 = q * kc, p2 = q * kp;
#pragma unroll
  for (int off = 32; off > 0; off >>= 1) {
    p0 += __shfl_xor(p0, off, 64);
    p1 += __shfl_xor(p1, off, 64);
    p2 += __shfl_xor(p2, off, 64);
  }

  const float s0 = (i > 0) ? p0 : 0.f;
  const float s1 = p1;
  const float s2 = (i < NTOK - 1) ? p2 : 0.f;
  const float m  = fmaxf(fmaxf(s0, s1), fmaxf(s2, 0.f));
  const float e0 = expf(s0 - m);
  const float e1 = expf(s1 - m);
  const float e2 = expf(s2 - m);
  const float ez = expf(-m);
  const float Z  = e0 + e1 + e2 + (float)(NTOK - 3) * ez;

  const size_t vb = ((size_t)b * NTOK) * CN + 128;
  const float v0 = C[vb + lane];
  const float v1 = C[vb + CN + lane];
  const float v2 = C[vb + 2 * (size_t)CN + lane];
  const float vs = Vsum[b * 64 + lane];

  out[(size_t)r * 64 + lane] =
      (e0 * v0 + e1 * v1 + e2 * v2 + ez * (vs - v0 - v1 - v2)) / Z;
}

// ---------------------------------------------------------------------------
extern "C" void kernel_launch(void* const* d_in, const int* in_sizes, int n_in,
                              void* d_out, int out_size, void* d_ws, size_t ws_size,
                              hipStream_t stream) {
  const float* x  = (const float*)d_in[0];
  const float* Wq = (const float*)d_in[1];
  const float* bq = (const float*)d_in[2];
  const float* Wk = (const float*)d_in[3];
  const float* bk = (const float*)d_in[4];
  const float* Wv = (const float*)d_in[5];
  const float* bv = (const float*)d_in[6];
  float* out = (float*)d_out;

  float* C    = (float*)d_ws;                 // ROWS x 192 (12 MiB)
  float* Vsum = C + (size_t)ROWS * CN;        // 4 x 64

  hipMemsetAsync(Vsum, 0, NB * 64 * sizeof(float), stream);
  qkv_gemm<<<ROWS / BM, 256, 0, stream>>>(x, Wq, bq, Wk, bk, Wv, bv, C);
  vsum_kernel<<<256, 256, 0, stream>>>(C, Vsum);
  attn_kernel<<<ROWS / 4, 256, 0, stream>>>(C, Vsum, out);
}

// Round 2
// 149.555 us; speedup vs baseline: 2.1582x; 2.1582x over previous
//
#include <hip/hip_runtime.h>
#include <math.h>

#define EMBED 768
#define NTOK  4096
#define NB    4
#define ROWS  16384          // 4 * 4096
#define CN    192            // Q(64)|K(64)|V(64)

typedef __attribute__((ext_vector_type(8))) short bf16x8;   // 8 bf16 = 4 VGPR
typedef __attribute__((ext_vector_type(4))) float f32x4;    // MFMA acc

// Split fp32 into h + l bf16 (round-nearest-even both): f ~= h + l, err ~2^-17 rel.
__device__ inline void split2(float f, short& h, short& l) {
  union { float f; unsigned u; } a; a.f = f;
  unsigned r = (a.u + 0x7FFFu + ((a.u >> 16) & 1u)) & 0xFFFF0000u;
  h = (short)(r >> 16);
  union { unsigned u; float f; } hf; hf.u = r;
  union { float f; unsigned u; } b; b.f = f - hf.f;
  l = (short)((b.u + 0x7FFFu + ((b.u >> 16) & 1u)) >> 16);
}

// ---------------------------------------------------------------------------
// W prep: Wt[plane][n][k] bf16, plane 0 = high, 1 = low. n in [0,192), k in [0,768).
// Writes coalesced (k fast); reads strided but tiny + L2/L3-absorbed.
// ---------------------------------------------------------------------------
__global__ __launch_bounds__(256) void wprep(const float* __restrict__ Wq,
                                             const float* __restrict__ Wk,
                                             const float* __restrict__ Wv,
                                             unsigned short* __restrict__ Wt) {
  int t = blockIdx.x * 256 + threadIdx.x;   // t = n*768 + k, exactly 192*768 threads
  int n = t / 768, k = t - n * 768;
  float w;
  if (n < 64)        w = Wq[k * 64 + n];
  else if (n < 128)  w = Wk[k * 64 + (n - 64)];
  else               w = Wv[k * 64 + (n - 128)];
  short h, l; split2(w, h, l);
  Wt[(size_t)n * 768 + k]         = (unsigned short)h;
  Wt[(size_t)(192 + n) * 768 + k] = (unsigned short)l;
}

// ---------------------------------------------------------------------------
// MFMA GEMM: C[16384][192] = x @ W + bias via split-bf16 (3 passes in one loop).
// No LDS, no barriers. 512 blocks x 128 threads (2 waves). Wave tile 32x96:
// m_t=2, n_t=6 tiles of 16x16x32. A frags direct from x (fp32 -> h/l in reg),
// B frags direct from Wt (L2-resident). 1-deep software pipeline on k.
// ---------------------------------------------------------------------------
__global__ __launch_bounds__(128) void qkv_mfma(const float* __restrict__ x,
                                                const unsigned short* __restrict__ Wtu,
                                                const float* __restrict__ bq,
                                                const float* __restrict__ bk,
                                                const float* __restrict__ bv,
                                                float* __restrict__ C) {
  const int lane = threadIdx.x & 63;
  const int wn   = threadIdx.x >> 6;   // 0..1 : n-half of the block
  const int ml   = lane & 15;          // free-dim index within frag
  const int q    = lane >> 4;          // quad: k = q*8 + j
  const int r0   = blockIdx.x * 32;
  const int nbase = wn * 96;

  f32x4 acc[2][6] = {};

  const float* xa0 = x + (size_t)(r0 + ml) * EMBED + q * 8;        // m-tile 0
  const float* xa1 = x + (size_t)(r0 + 16 + ml) * EMBED + q * 8;   // m-tile 1
  const bf16x8* wt = (const bf16x8*)Wtu;

  // B row base indices in bf16x8 units: (plane*192 + n)*96 + q  (+ ks*4 per step)
  int bidx[12];
#pragma unroll
  for (int p = 0; p < 2; ++p)
#pragma unroll
    for (int nt = 0; nt < 6; ++nt)
      bidx[p * 6 + nt] = (p * 192 + nbase + nt * 16 + ml) * 96 + q;

  float4 ca[4]; bf16x8 cb[12];
  ca[0] = *(const float4*)(xa0);     ca[1] = *(const float4*)(xa0 + 4);
  ca[2] = *(const float4*)(xa1);     ca[3] = *(const float4*)(xa1 + 4);
#pragma unroll
  for (int j = 0; j < 12; ++j) cb[j] = wt[bidx[j]];

  for (int ks = 0; ks < 24; ++ks) {
    float4 na[4]; bf16x8 nb[12];
    if (ks < 23) {
      const float* p0 = xa0 + (ks + 1) * 32;
      const float* p1 = xa1 + (ks + 1) * 32;
      na[0] = *(const float4*)(p0);  na[1] = *(const float4*)(p0 + 4);
      na[2] = *(const float4*)(p1);  na[3] = *(const float4*)(p1 + 4);
#pragma unroll
      for (int j = 0; j < 12; ++j) nb[j] = wt[bidx[j] + (ks + 1) * 4];
    }

    // convert current A to h/l frags
    bf16x8 ah0, al0, ah1, al1;
    {
      float f0[8] = {ca[0].x, ca[0].y, ca[0].z, ca[0].w,
                     ca[1].x, ca[1].y, ca[1].z, ca[1].w};
      float f1[8] = {ca[2].x, ca[2].y, ca[2].z, ca[2].w,
                     ca[3].x, ca[3].y, ca[3].z, ca[3].w};
#pragma unroll
      for (int j = 0; j < 8; ++j) {
        short h, l;
        split2(f0[j], h, l); ah0[j] = h; al0[j] = l;
        split2(f1[j], h, l); ah1[j] = h; al1[j] = l;
      }
    }

#pragma unroll
    for (int nt = 0; nt < 6; ++nt) {
      bf16x8 bh = cb[nt], bl = cb[6 + nt];
      acc[0][nt] = __builtin_amdgcn_mfma_f32_16x16x32_bf16(ah0, bh, acc[0][nt], 0, 0, 0);
      acc[0][nt] = __builtin_amdgcn_mfma_f32_16x16x32_bf16(ah0, bl, acc[0][nt], 0, 0, 0);
      acc[0][nt] = __builtin_amdgcn_mfma_f32_16x16x32_bf16(al0, bh, acc[0][nt], 0, 0, 0);
      acc[1][nt] = __builtin_amdgcn_mfma_f32_16x16x32_bf16(ah1, bh, acc[1][nt], 0, 0, 0);
      acc[1][nt] = __builtin_amdgcn_mfma_f32_16x16x32_bf16(ah1, bl, acc[1][nt], 0, 0, 0);
      acc[1][nt] = __builtin_amdgcn_mfma_f32_16x16x32_bf16(al1, bh, acc[1][nt], 0, 0, 0);
    }

#pragma unroll
    for (int j = 0; j < 4; ++j)  ca[j] = na[j];
#pragma unroll
    for (int j = 0; j < 12; ++j) cb[j] = nb[j];
  }

  // epilogue: bias + store. C/D layout: col = lane&15, row = q*4 + reg.
#pragma unroll
  for (int nt = 0; nt < 6; ++nt) {
    int n = nbase + nt * 16 + ml;
    float bias = (n < 64) ? bq[n] : (n < 128) ? bk[n - 64] : bv[n - 128];
#pragma unroll
    for (int mt = 0; mt < 2; ++mt) {
#pragma unroll
      for (int reg = 0; reg < 4; ++reg) {
        int row = r0 + mt * 16 + q * 4 + reg;
        C[(size_t)row * CN + n] = acc[mt][nt][reg] + bias;
      }
    }
  }
}

// ---------------------------------------------------------------------------
// Vsum[b][d] = sum_r V[b,r,d]
// ---------------------------------------------------------------------------
__global__ __launch_bounds__(256) void vsum_kernel(const float* __restrict__ C,
                                                   float* __restrict__ Vsum) {
  __shared__ float red[4][64];
  const int t = threadIdx.x;
  const int d = t & 63;
  const int g = t >> 6;
  const int batch = blockIdx.x >> 6;
  const int chunk = blockIdx.x & 63;
  const size_t base =
      ((size_t)batch * NTOK + (size_t)chunk * 64 + (size_t)g * 16) * CN + 128 + d;
  float s = 0.f;
#pragma unroll
  for (int rr = 0; rr < 16; ++rr) s += C[base + (size_t)rr * CN];
  red[g][d] = s;
  __syncthreads();
  if (g == 0) {
    atomicAdd(&Vsum[batch * 64 + d],
              red[0][d] + red[1][d] + red[2][d] + red[3][d]);
  }
}

// ---------------------------------------------------------------------------
// Per-row scores + softmax-with-zero-background + V combine (faithful quirk).
// ---------------------------------------------------------------------------
__global__ __launch_bounds__(256) void attn_kernel(const float* __restrict__ C,
                                                   const float* __restrict__ Vsum,
                                                   float* __restrict__ out) {
  const int t    = threadIdx.x;
  const int lane = t & 63;
  const int wave = t >> 6;
  const int r = blockIdx.x * 4 + wave;
  const int b = r >> 12;
  const int i = r & (NTOK - 1);

  const float q  = C[(size_t)r * CN + lane];
  const float kc = C[(size_t)r * CN + 64 + lane];
  float km = 0.f, kp = 0.f;
  if (i > 0)        km = C[(size_t)(r - 1) * CN + 64 + lane];
  if (i < NTOK - 1) kp = C[(size_t)(r + 1) * CN + 64 + lane];

  float p0 = q * km, p1 = q * kc, p2 = q * kp;
#pragma unroll
  for (int off = 32; off > 0; off >>= 1) {
    p0 += __shfl_xor(p0, off, 64);
    p1 += __shfl_xor(p1, off, 64);
    p2 += __shfl_xor(p2, off, 64);
  }

  const float s0 = (i > 0) ? p0 : 0.f;
  const float s1 = p1;
  const float s2 = (i < NTOK - 1) ? p2 : 0.f;
  const float m  = fmaxf(fmaxf(s0, s1), fmaxf(s2, 0.f));
  const float e0 = expf(s0 - m);
  const float e1 = expf(s1 - m);
  const float e2 = expf(s2 - m);
  const float ez = expf(-m);
  const float Z  = e0 + e1 + e2 + (float)(NTOK - 3) * ez;

  const size_t vb = ((size_t)b * NTOK) * CN + 128;
  const float v0 = C[vb + lane];
  const float v1 = C[vb + CN + lane];
  const float v2 = C[vb + 2 * (size_t)CN + lane];
  const float vs = Vsum[b * 64 + lane];

  out[(size_t)r * 64 + lane] =
      (e0 * v0 + e1 * v1 + e2 * v2 + ez * (vs - v0 - v1 - v2)) / Z;
}

// ---------------------------------------------------------------------------
extern "C" void kernel_launch(void* const* d_in, const int* in_sizes, int n_in,
                              void* d_out, int out_size, void* d_ws, size_t ws_size,
                              hipStream_t stream) {
  const float* x  = (const float*)d_in[0];
  const float* Wq = (const float*)d_in[1];
  const float* bq = (const float*)d_in[2];
  const float* Wk = (const float*)d_in[3];
  const float* bk = (const float*)d_in[4];
  const float* Wv = (const float*)d_in[5];
  const float* bv = (const float*)d_in[6];
  float* out = (float*)d_out;

  float* C    = (float*)d_ws;                       // 16384 x 192 fp32 (12 MiB)
  float* Vsum = C + (size_t)ROWS * CN;              // 4 x 64
  unsigned short* Wt = (unsigned short*)(Vsum + NB * 64);  // 2 x 192 x 768 bf16 (576 KiB)

  hipMemsetAsync(Vsum, 0, NB * 64 * sizeof(float), stream);
  wprep<<<576, 256, 0, stream>>>(Wq, Wk, Wv, Wt);
  qkv_mfma<<<512, 128, 0, stream>>>(x, Wt, bq, bk, bv, C);
  vsum_kernel<<<256, 256, 0, stream>>>(C, Vsum);
  attn_kernel<<<ROWS / 4, 256, 0, stream>>>(C, Vsum, out);
}